// Round 2
// baseline (393.498 us; speedup 1.0000x reference)
//
#include <hip/hip_runtime.h>

typedef float f32x4 __attribute__((ext_vector_type(4)));
typedef long i64;

#define KDIM 512
#define NDIM 512
#define LDS_STRIDE 520   // A-tile: 512 + 8B pad -> row-to-row bank offset 2 -> conflict-free b64 reads
#define OUT_STRIDE 260   // epilogue slab: 256 + 4 floats pad -> rows shift 4 banks -> conflict-free

__device__ __forceinline__ float clamp448(float v) {
    return fminf(fmaxf(v, -448.0f), 448.0f);
}

// ---------------- Kernel 1: per-block partial abs-max (no atomics) --------------------------
// Blocks 0..4095 cover x, 4096..4127 cover w. Partials land in contention-free slots;
// consumers (wquant, gemm) finalize the 16KB partial array themselves -> no serial
// single-block reduce dispatch on the critical path.
__global__ __launch_bounds__(256) void amax_kernel(const float4* __restrict__ x,
                                                   const float4* __restrict__ w,
                                                   float* __restrict__ partial) {
    const int tid = threadIdx.x;
    float m = 0.0f;
    if (blockIdx.x < 4096) {
        int base = blockIdx.x * 256 + tid;
        #pragma unroll
        for (int j = 0; j < 8; ++j) {
            float4 v = x[base + j * 1048576];
            m = fmaxf(m, fmaxf(fmaxf(fabsf(v.x), fabsf(v.y)), fmaxf(fabsf(v.z), fabsf(v.w))));
        }
    } else {
        int base = (blockIdx.x - 4096) * 256 + tid;
        #pragma unroll
        for (int j = 0; j < 8; ++j) {
            float4 v = w[base + j * 8192];
            m = fmaxf(m, fmaxf(fmaxf(fabsf(v.x), fabsf(v.y)), fmaxf(fabsf(v.z), fabsf(v.w))));
        }
    }
    #pragma unroll
    for (int off = 32; off > 0; off >>= 1)
        m = fmaxf(m, __shfl_down(m, off, 64));
    __shared__ float red[4];
    const int wave = tid >> 6, lane = tid & 63;
    if (lane == 0) red[wave] = m;
    __syncthreads();
    if (tid == 0)
        partial[blockIdx.x] = fmaxf(fmaxf(red[0], red[1]), fmaxf(red[2], red[3]));
}

// ---------------- Kernel 2: quantize weight [K,N] fp32 -> w_fp8 [N,K] e4m3 ------------------
// Self-finalizes the 32 w-partials (128 B read) -> no dependency on a reduce kernel.
__global__ __launch_bounds__(256) void wquant_kernel(const float4* __restrict__ wv,
                                                     const float* __restrict__ partial,
                                                     unsigned char* __restrict__ wq) {
    const int tid = threadIdx.x;
    __shared__ float swm;
    float mw = (tid < 32) ? partial[4096 + tid] : 0.0f;
    #pragma unroll
    for (int off = 32; off > 0; off >>= 1)
        mw = fmaxf(mw, __shfl_down(mw, off, 64));
    if (tid == 0) swm = mw;
    __syncthreads();
    const float ws = 448.0f / fmaxf(swm, 1e-12f);
    #pragma unroll
    for (int j = 0; j < 4; ++j) {
        const int idx = blockIdx.x * 1024 + j * 256 + tid;  // 65,536 float4 total
        const int k = idx >> 7;          // w row (K), 128 float4 per row
        const int n4 = idx & 127;        // float4 within row
        float4 v = wv[idx];
        float a[4] = {v.x, v.y, v.z, v.w};
        #pragma unroll
        for (int i = 0; i < 4; ++i) {
            float q = clamp448(a[i] * ws);
            int p = __builtin_amdgcn_cvt_pk_fp8_f32(q, q, 0, false);
            wq[(n4 * 4 + i) * KDIM + k] = (unsigned char)(p & 0xff);
        }
    }
}

// ---------------- Kernel 3: fused x-quant + fp8 MFMA GEMM + dequant -------------------------
// Round-0 lesson: direct 64B-granular stores RFO'd +71MB of output lines -> LDS-staged
// full-line float4 stores are mandatory. This round raises occupancy instead:
// 32-row blocks -> acc 32 regs/lane, LDS 16,640(A) + 8,320(epilogue) = 24,960 B.
// __launch_bounds__(256,5): 5 blocks/CU = 20 waves/CU (vs 12 before).
__global__ __launch_bounds__(256, 5) void gemm_kernel(const float* __restrict__ x,
                                                      const unsigned char* __restrict__ wq,
                                                      const float* __restrict__ partial,
                                                      float* __restrict__ out) {
    __shared__ unsigned char lds_a[32 * LDS_STRIDE];  // 16,640 B
    __shared__ float lds_o[8 * OUT_STRIDE];           // 8,320 B (8-row slab)
    __shared__ float red[8];
    const int tid = threadIdx.x;
    const int wave = tid >> 6, lane = tid & 63;

    // ---- per-block finalize of amax partials (identical result in every block) ----
    float px = 0.0f;
    #pragma unroll
    for (int j = 0; j < 16; ++j)
        px = fmaxf(px, partial[tid + 256 * j]);
    float pw = (tid < 32) ? partial[4096 + tid] : 0.0f;
    #pragma unroll
    for (int off = 32; off > 0; off >>= 1) {
        px = fmaxf(px, __shfl_down(px, off, 64));
        pw = fmaxf(pw, __shfl_down(pw, off, 64));
    }
    if (lane == 0) { red[wave] = px; red[4 + wave] = pw; }
    __syncthreads();
    const float ax = fmaxf(fmaxf(fmaxf(red[0], red[1]), fmaxf(red[2], red[3])), 1e-12f);
    const float aw = fmaxf(fmaxf(fmaxf(red[4], red[5]), fmaxf(red[6], red[7])), 1e-12f);
    const float xs = 448.0f / ax;
    const float ws = 448.0f / aw;
    const float inv = (1.0f / xs) * (1.0f / ws);   // mirror reference dequant arithmetic

    // ---- stage: 32x512 fp32 -> fp8 into LDS (4,096 float4, 16 per thread, coalesced) ----
    const long m0 = (long)blockIdx.x * 32;
    const float4* xv = (const float4*)(x + m0 * KDIM);
    #pragma unroll 8
    for (int j = 0; j < 16; ++j) {
        int f4i = tid + 256 * j;
        float4 v = xv[f4i];
        int row = f4i >> 7;             // 128 float4 per row
        int colb = (f4i & 127) << 2;    // byte column
        float a0 = clamp448(v.x * xs);
        float a1 = clamp448(v.y * xs);
        float a2 = clamp448(v.z * xs);
        float a3 = clamp448(v.w * xs);
        int p = __builtin_amdgcn_cvt_pk_fp8_f32(a0, a1, 0, false);
        p = __builtin_amdgcn_cvt_pk_fp8_f32(a2, a3, p, true);
        *(unsigned*)&lds_a[row * LDS_STRIDE + colb] = (unsigned)p;
    }
    __syncthreads();

    const int ln = lane & 15, lg = lane >> 4;
    const int kofs = lg * 8;
    float* outp = out + m0 * NDIM;

    for (int chunk = 0; chunk < 2; ++chunk) {
        const int nbase = chunk * 256 + wave * 64;
        f32x4 acc[2][4];
        #pragma unroll
        for (int a = 0; a < 2; ++a)
            #pragma unroll
            for (int b = 0; b < 4; ++b)
                acc[a][b] = (f32x4){0.0f, 0.0f, 0.0f, 0.0f};

        for (int ks = 0; ks < 16; ++ks) {
            const int kb = ks * 32 + kofs;
            i64 af[2], bf[4];
            #pragma unroll
            for (int t = 0; t < 2; ++t)
                af[t] = *(const i64*)&lds_a[(t * 16 + ln) * LDS_STRIDE + kb];
            #pragma unroll
            for (int t = 0; t < 4; ++t)
                bf[t] = *(const i64*)&wq[(nbase + t * 16 + ln) * KDIM + kb];
            #pragma unroll
            for (int tm = 0; tm < 2; ++tm)
                #pragma unroll
                for (int tn = 0; tn < 4; ++tn)
                    acc[tm][tn] = __builtin_amdgcn_mfma_f32_16x16x32_fp8_fp8(
                        af[tm], bf[tn], acc[tm][tn], 0, 0, 0);
        }

        // ---- epilogue: 8-row LDS slabs -> full-line 1KB-contiguous float4 stores ----
        // C/D layout: col = lane&15, row = (lane>>4)*4 + reg. Slab h holds rows with lg>>1==h.
        #pragma unroll 1
        for (int tm = 0; tm < 2; ++tm) {
            #pragma unroll 1
            for (int h = 0; h < 2; ++h) {
                __syncthreads();   // previous slab's reads done before overwrite
                if ((lg >> 1) == h) {
                    #pragma unroll
                    for (int tn = 0; tn < 4; ++tn) {
                        const int c = wave * 64 + tn * 16 + ln;
                        #pragma unroll
                        for (int r = 0; r < 4; ++r)
                            lds_o[((lg & 1) * 4 + r) * OUT_STRIDE + c] = acc[tm][tn][r] * inv;
                    }
                }
                __syncthreads();
                // 8 rows x 256 cols = 512 float4; each wave stores contiguous 1 KB half-rows
                #pragma unroll
                for (int j = 0; j < 2; ++j) {
                    const int idx = j * 256 + tid;
                    const int rr = idx >> 6;       // 0..7
                    const int c4 = idx & 63;       // float4 within half-row
                    float4 v = *(const float4*)&lds_o[rr * OUT_STRIDE + c4 * 4];
                    *(float4*)&outp[(long)(tm * 16 + h * 8 + rr) * NDIM + chunk * 256 + c4 * 4] = v;
                }
            }
        }
    }
}

extern "C" void kernel_launch(void* const* d_in, const int* in_sizes, int n_in,
                              void* d_out, int out_size, void* d_ws, size_t ws_size,
                              hipStream_t stream) {
    const float* x = (const float*)d_in[0];
    const float* w = (const float*)d_in[1];
    float* out = (float*)d_out;
    unsigned char* wq = (unsigned char*)d_ws + 256;                 // 262,144 B fp8 weight [N,K]
    float* partial = (float*)((char*)d_ws + 256 + 262144);          // 4128 floats partial maxes
    const int M = in_sizes[0] / KDIM;                               // 65536

    amax_kernel<<<4096 + 32, 256, 0, stream>>>((const float4*)x, (const float4*)w, partial);
    wquant_kernel<<<64, 256, 0, stream>>>((const float4*)w, partial, wq);
    gemm_kernel<<<M / 32, 256, 0, stream>>>(x, wq, partial, out);
}

// Round 3
// 308.898 us; speedup vs baseline: 1.2739x; 1.2739x over previous
//
#include <hip/hip_runtime.h>

typedef float f32x4 __attribute__((ext_vector_type(4)));
typedef long i64;

#define KDIM 512
#define NDIM 512
#define LDS_STRIDE 520   // fallback A-tile stride
#define OUT_STRIDE 260   // fallback epilogue stride

__device__ __forceinline__ float clamp448(float v) {
    return fminf(fmaxf(v, -448.0f), 448.0f);
}

__device__ __forceinline__ void gload_lds16(const void* g, void* l) {
    // async global->LDS, 16B per lane; LDS dest = wave-uniform base + lane*16
    __builtin_amdgcn_global_load_lds((const __attribute__((address_space(1))) unsigned*)g,
                                     (__attribute__((address_space(3))) unsigned*)l, 16, 0, 0);
}

// ---------------- Kernel 1: per-block partial abs-max (no atomics) --------------------------
__global__ __launch_bounds__(256) void amax_kernel(const float4* __restrict__ x,
                                                   const float4* __restrict__ w,
                                                   float* __restrict__ partial) {
    const int tid = threadIdx.x;
    float m = 0.0f;
    if (blockIdx.x < 4096) {
        int base = blockIdx.x * 256 + tid;
        #pragma unroll
        for (int j = 0; j < 8; ++j) {
            float4 v = x[base + j * 1048576];
            m = fmaxf(m, fmaxf(fmaxf(fabsf(v.x), fabsf(v.y)), fmaxf(fabsf(v.z), fabsf(v.w))));
        }
    } else {
        int base = (blockIdx.x - 4096) * 256 + tid;
        #pragma unroll
        for (int j = 0; j < 8; ++j) {
            float4 v = w[base + j * 8192];
            m = fmaxf(m, fmaxf(fmaxf(fabsf(v.x), fabsf(v.y)), fmaxf(fabsf(v.z), fabsf(v.w))));
        }
    }
    #pragma unroll
    for (int off = 32; off > 0; off >>= 1)
        m = fmaxf(m, __shfl_down(m, off, 64));
    __shared__ float red[4];
    const int wave = tid >> 6, lane = tid & 63;
    if (lane == 0) red[wave] = m;
    __syncthreads();
    if (tid == 0)
        partial[blockIdx.x] = fmaxf(fmaxf(red[0], red[1]), fmaxf(red[2], red[3]));
}

// ---------------- Kernel 2: quantize x -> xq [M,K] fp8 AND w -> wq [N,K] fp8 ----------------
// First (grid-64) blocks handle x; last 64 blocks transpose-quantize w. Block 0 / first
// w-block publish the finalized amax values to scales[0..1] for the gemm.
__global__ __launch_bounds__(256) void quant_kernel(const float4* __restrict__ xv,
                                                    const float4* __restrict__ wv,
                                                    const float* __restrict__ partial,
                                                    unsigned char* __restrict__ xq,
                                                    unsigned char* __restrict__ wq,
                                                    float* __restrict__ scales) {
    const int tid = threadIdx.x;
    __shared__ float red[4];
    const int nxblocks = gridDim.x - 64;
    if ((int)blockIdx.x < nxblocks) {
        // finalize x amax (identical in every block; partials are L2-resident)
        float px = 0.0f;
        #pragma unroll
        for (int j = 0; j < 16; ++j)
            px = fmaxf(px, partial[tid + 256 * j]);
        #pragma unroll
        for (int off = 32; off > 0; off >>= 1)
            px = fmaxf(px, __shfl_down(px, off, 64));
        const int wave = tid >> 6, lane = tid & 63;
        if (lane == 0) red[wave] = px;
        __syncthreads();
        const float ax = fmaxf(fmaxf(fmaxf(red[0], red[1]), fmaxf(red[2], red[3])), 1e-12f);
        const float xs = 448.0f / ax;
        if (blockIdx.x == 0 && tid == 0) scales[0] = ax;
        const int base = blockIdx.x * 4096;   // float4 units; 4096 per block
        #pragma unroll 4
        for (int j = 0; j < 16; ++j) {
            const int idx = base + j * 256 + tid;
            float4 v = xv[idx];
            int p = __builtin_amdgcn_cvt_pk_fp8_f32(clamp448(v.x * xs), clamp448(v.y * xs), 0, false);
            p = __builtin_amdgcn_cvt_pk_fp8_f32(clamp448(v.z * xs), clamp448(v.w * xs), p, true);
            ((unsigned*)xq)[idx] = (unsigned)p;   // coalesced 256B per wave
        }
    } else {
        // ---- w path: finalize w amax, transpose-quantize [K,N] -> [N,K] ----
        float mw = (tid < 32) ? partial[4096 + tid] : 0.0f;
        #pragma unroll
        for (int off = 32; off > 0; off >>= 1)
            mw = fmaxf(mw, __shfl_down(mw, off, 64));
        if (tid == 0) red[0] = mw;
        __syncthreads();
        const float aw = fmaxf(red[0], 1e-12f);
        const float ws = 448.0f / aw;
        const int wb = blockIdx.x - nxblocks;
        if (wb == 0 && tid == 0) scales[1] = aw;
        #pragma unroll
        for (int j = 0; j < 4; ++j) {
            const int idx = wb * 1024 + j * 256 + tid;  // 65,536 float4 total
            const int k = idx >> 7;
            const int n4 = idx & 127;
            float4 v = wv[idx];
            float a[4] = {v.x, v.y, v.z, v.w};
            #pragma unroll
            for (int i = 0; i < 4; ++i) {
                float q = clamp448(a[i] * ws);
                int p = __builtin_amdgcn_cvt_pk_fp8_f32(q, q, 0, false);
                wq[(n4 * 4 + i) * KDIM + k] = (unsigned char)(p & 0xff);
            }
        }
    }
}

// ---------------- Kernel 3: m97-structure fp8 GEMM ------------------------------------------
// 128x128 tile, BK=64, 4 waves (2x2), 4x4 16x16x32 fragments per wave. Both operands staged
// via global_load_lds width-16 into double-buffered linear LDS; 2 barriers per K-step.
// Epilogue: LDS-staged 32-row slabs -> full-line float4 stores (round-1 lesson: partial-line
// global stores RFO-fetch the output).
__device__ __forceinline__ void compute_step(const unsigned char* __restrict__ A,
                                             const unsigned char* __restrict__ Bt,
                                             int wr, int wc, int ln, int lg,
                                             f32x4 (&acc)[4][4]) {
    #pragma unroll
    for (int ksub = 0; ksub < 2; ++ksub) {
        const int kb = ksub * 32 + lg * 8;
        i64 af[4], bf[4];
        #pragma unroll
        for (int t = 0; t < 4; ++t)
            af[t] = *(const i64*)&A[(wr * 64 + t * 16 + ln) * 64 + kb];
        #pragma unroll
        for (int t = 0; t < 4; ++t)
            bf[t] = *(const i64*)&Bt[(wc * 64 + t * 16 + ln) * 64 + kb];
        #pragma unroll
        for (int tm = 0; tm < 4; ++tm)
            #pragma unroll
            for (int tn = 0; tn < 4; ++tn)
                acc[tm][tn] = __builtin_amdgcn_mfma_f32_16x16x32_fp8_fp8(
                    af[tm], bf[tn], acc[tm][tn], 0, 0, 0);
    }
}

__global__ __launch_bounds__(256, 4) void gemm_kernel(const unsigned char* __restrict__ xq,
                                                      const unsigned char* __restrict__ wq,
                                                      const float* __restrict__ scales,
                                                      float* __restrict__ out) {
    __shared__ __align__(16) unsigned char lds[32768];  // A0|B0|A1|B1, 8KB each
    const int tid = threadIdx.x;
    const int wave = tid >> 6, lane = tid & 63;
    const int ln = lane & 15, lg = lane >> 4;
    const int wr = wave >> 1, wc = wave & 1;

    // XCD-chunked bijective swizzle (2048 % 8 == 0): the 4 ntile-blocks sharing an
    // xq panel get consecutive vb on the SAME XCD -> panel L2-hits.
    const int bid = blockIdx.x;
    const int vb = (bid & 7) * 256 + (bid >> 3);
    const long m0 = (long)(vb >> 2) * 128;
    const int n0 = (vb & 3) * 128;

    const float ax = fmaxf(scales[0], 1e-12f);
    const float aw = fmaxf(scales[1], 1e-12f);
    const float xs = 448.0f / ax;
    const float ws = 448.0f / aw;
    const float inv = (1.0f / xs) * (1.0f / ws);

    // per-thread global staging addresses (rows tid>>2 and 64+(tid>>2), 16B column tid&3)
    const unsigned char* gA = xq + (m0 + (tid >> 2)) * KDIM + (tid & 3) * 16;
    const unsigned char* gB = wq + (long)(n0 + (tid >> 2)) * KDIM + (tid & 3) * 16;
    unsigned char* const lw = lds + wave * 1024;  // wave-uniform LDS bases

    f32x4 acc[4][4];
    #pragma unroll
    for (int a = 0; a < 4; ++a)
        #pragma unroll
        for (int b = 0; b < 4; ++b)
            acc[a][b] = (f32x4){0.0f, 0.0f, 0.0f, 0.0f};

    // prologue: stage K-tile 0 into buf 0
    gload_lds16(gA,         lw);
    gload_lds16(gA + 32768, lw + 4096);
    gload_lds16(gB,         lw + 8192);
    gload_lds16(gB + 32768, lw + 12288);
    __syncthreads();

    #pragma unroll 1
    for (int kt = 0; kt < 7; ++kt) {
        // issue next tile's async loads into the other buffer
        const int nb = ((kt + 1) & 1) * 16384;
        const int ko = (kt + 1) * 64;
        gload_lds16(gA + ko,         lw + nb);
        gload_lds16(gA + ko + 32768, lw + nb + 4096);
        gload_lds16(gB + ko,         lw + nb + 8192);
        gload_lds16(gB + ko + 32768, lw + nb + 12288);
        // compute current buffer while loads fly
        const unsigned char* cb = lds + (kt & 1) * 16384;
        compute_step(cb, cb + 8192, wr, wc, ln, lg, acc);
        __syncthreads();   // drains vmcnt -> next buffer ready
    }
    compute_step(lds + 16384, lds + 16384 + 8192, wr, wc, ln, lg, acc);
    __syncthreads();       // LDS now reusable for epilogue

    // ---- epilogue: 4 slabs of 32 rows x 128 cols staged in LDS, full-line stores ----
    float* lo = (float*)lds;   // 32 x 132 floats = 16,896 B
    #pragma unroll
    for (int s = 0; s < 4; ++s) {
        if (wr == (s >> 1)) {
            #pragma unroll
            for (int tm2 = 0; tm2 < 2; ++tm2) {
                const int tm = (s & 1) * 2 + tm2;
                #pragma unroll
                for (int tn = 0; tn < 4; ++tn) {
                    const int col = wc * 64 + tn * 16 + ln;
                    #pragma unroll
                    for (int r = 0; r < 4; ++r)
                        lo[(tm2 * 16 + lg * 4 + r) * 132 + col] = acc[tm][tn][r] * inv;
                }
            }
        }
        __syncthreads();
        #pragma unroll
        for (int j = 0; j < 4; ++j) {
            const int idx = j * 256 + tid;
            const int rr = idx >> 5;       // 0..31
            const int c4 = idx & 31;       // float4 within 128-col row
            float4 v = *(const float4*)&lo[rr * 132 + c4 * 4];
            *(float4*)&out[(m0 + s * 32 + rr) * NDIM + n0 + c4 * 4] = v;
        }
        __syncthreads();
    }
}

// ================= fallback path (round-2, known-passing) if ws too small ==================
__global__ __launch_bounds__(256) void wquant_r2(const float4* __restrict__ wv,
                                                 const float* __restrict__ partial,
                                                 unsigned char* __restrict__ wq) {
    const int tid = threadIdx.x;
    __shared__ float swm;
    float mw = (tid < 32) ? partial[4096 + tid] : 0.0f;
    #pragma unroll
    for (int off = 32; off > 0; off >>= 1)
        mw = fmaxf(mw, __shfl_down(mw, off, 64));
    if (tid == 0) swm = mw;
    __syncthreads();
    const float ws = 448.0f / fmaxf(swm, 1e-12f);
    #pragma unroll
    for (int j = 0; j < 4; ++j) {
        const int idx = blockIdx.x * 1024 + j * 256 + tid;
        const int k = idx >> 7;
        const int n4 = idx & 127;
        float4 v = wv[idx];
        float a[4] = {v.x, v.y, v.z, v.w};
        #pragma unroll
        for (int i = 0; i < 4; ++i) {
            float q = clamp448(a[i] * ws);
            int p = __builtin_amdgcn_cvt_pk_fp8_f32(q, q, 0, false);
            wq[(n4 * 4 + i) * KDIM + k] = (unsigned char)(p & 0xff);
        }
    }
}

__global__ __launch_bounds__(256, 5) void gemm_r2(const float* __restrict__ x,
                                                  const unsigned char* __restrict__ wq,
                                                  const float* __restrict__ partial,
                                                  float* __restrict__ out) {
    __shared__ unsigned char lds_a[32 * LDS_STRIDE];
    __shared__ float lds_o[8 * OUT_STRIDE];
    __shared__ float red[8];
    const int tid = threadIdx.x;
    const int wave = tid >> 6, lane = tid & 63;
    float px = 0.0f;
    #pragma unroll
    for (int j = 0; j < 16; ++j)
        px = fmaxf(px, partial[tid + 256 * j]);
    float pw = (tid < 32) ? partial[4096 + tid] : 0.0f;
    #pragma unroll
    for (int off = 32; off > 0; off >>= 1) {
        px = fmaxf(px, __shfl_down(px, off, 64));
        pw = fmaxf(pw, __shfl_down(pw, off, 64));
    }
    if (lane == 0) { red[wave] = px; red[4 + wave] = pw; }
    __syncthreads();
    const float ax = fmaxf(fmaxf(fmaxf(red[0], red[1]), fmaxf(red[2], red[3])), 1e-12f);
    const float aw = fmaxf(fmaxf(fmaxf(red[4], red[5]), fmaxf(red[6], red[7])), 1e-12f);
    const float xs = 448.0f / ax;
    const float ws = 448.0f / aw;
    const float inv = (1.0f / xs) * (1.0f / ws);
    const long m0 = (long)blockIdx.x * 32;
    const float4* xv = (const float4*)(x + m0 * KDIM);
    #pragma unroll 8
    for (int j = 0; j < 16; ++j) {
        int f4i = tid + 256 * j;
        float4 v = xv[f4i];
        int row = f4i >> 7;
        int colb = (f4i & 127) << 2;
        int p = __builtin_amdgcn_cvt_pk_fp8_f32(clamp448(v.x * xs), clamp448(v.y * xs), 0, false);
        p = __builtin_amdgcn_cvt_pk_fp8_f32(clamp448(v.z * xs), clamp448(v.w * xs), p, true);
        *(unsigned*)&lds_a[row * LDS_STRIDE + colb] = (unsigned)p;
    }
    __syncthreads();
    const int ln = lane & 15, lg = lane >> 4;
    const int kofs = lg * 8;
    float* outp = out + m0 * NDIM;
    for (int chunk = 0; chunk < 2; ++chunk) {
        const int nbase = chunk * 256 + wave * 64;
        f32x4 acc[2][4];
        #pragma unroll
        for (int a = 0; a < 2; ++a)
            #pragma unroll
            for (int b = 0; b < 4; ++b)
                acc[a][b] = (f32x4){0.0f, 0.0f, 0.0f, 0.0f};
        for (int ks = 0; ks < 16; ++ks) {
            const int kb = ks * 32 + kofs;
            i64 af[2], bf[4];
            #pragma unroll
            for (int t = 0; t < 2; ++t)
                af[t] = *(const i64*)&lds_a[(t * 16 + ln) * LDS_STRIDE + kb];
            #pragma unroll
            for (int t = 0; t < 4; ++t)
                bf[t] = *(const i64*)&wq[(nbase + t * 16 + ln) * KDIM + kb];
            #pragma unroll
            for (int tm = 0; tm < 2; ++tm)
                #pragma unroll
                for (int tn = 0; tn < 4; ++tn)
                    acc[tm][tn] = __builtin_amdgcn_mfma_f32_16x16x32_fp8_fp8(
                        af[tm], bf[tn], acc[tm][tn], 0, 0, 0);
        }
        #pragma unroll 1
        for (int tm = 0; tm < 2; ++tm) {
            #pragma unroll 1
            for (int h = 0; h < 2; ++h) {
                __syncthreads();
                if ((lg >> 1) == h) {
                    #pragma unroll
                    for (int tn = 0; tn < 4; ++tn) {
                        const int c = wave * 64 + tn * 16 + ln;
                        #pragma unroll
                        for (int r = 0; r < 4; ++r)
                            lds_o[((lg & 1) * 4 + r) * OUT_STRIDE + c] = acc[tm][tn][r] * inv;
                    }
                }
                __syncthreads();
                #pragma unroll
                for (int j = 0; j < 2; ++j) {
                    const int idx = j * 256 + tid;
                    const int rr = idx >> 6;
                    const int c4 = idx & 63;
                    float4 v = *(const float4*)&lds_o[rr * OUT_STRIDE + c4 * 4];
                    *(float4*)&outp[(long)(tm * 16 + h * 8 + rr) * NDIM + chunk * 256 + c4 * 4] = v;
                }
            }
        }
    }
}

extern "C" void kernel_launch(void* const* d_in, const int* in_sizes, int n_in,
                              void* d_out, int out_size, void* d_ws, size_t ws_size,
                              hipStream_t stream) {
    const float* x = (const float*)d_in[0];
    const float* w = (const float*)d_in[1];
    float* out = (float*)d_out;
    float* scales = (float*)d_ws;                                   // [0]=x_amax, [1]=w_amax
    unsigned char* wq = (unsigned char*)d_ws + 256;                 // 262,144 B  [N,K] fp8
    float* partial = (float*)((char*)d_ws + 262400);                // 4128 partial maxes
    unsigned char* xq = (unsigned char*)d_ws + 524288;              // M*K fp8 = 33.5 MB
    const int M = in_sizes[0] / KDIM;                               // 65536
    const size_t need = 524288 + (size_t)M * KDIM;

    amax_kernel<<<4096 + 32, 256, 0, stream>>>((const float4*)x, (const float4*)w, partial);
    if (ws_size >= need) {
        quant_kernel<<<M / 32 + 64, 256, 0, stream>>>((const float4*)x, (const float4*)w,
                                                      partial, xq, wq, scales);
        gemm_kernel<<<(M / 128) * 4, 256, 0, stream>>>(xq, wq, scales, out);
    } else {
        wquant_r2<<<64, 256, 0, stream>>>((const float4*)w, partial, wq);
        gemm_r2<<<M / 32, 256, 0, stream>>>(x, wq, partial, out);
    }
}